// Round 7
// baseline (1086.256 us; speedup 1.0000x reference)
//
#include <hip/hip_runtime.h>
#include <hip/hip_fp16.h>
#include <hip/hip_cooperative_groups.h>

namespace cg = cooperative_groups;

// VecInt: scaling-and-squaring integration of stationary velocity field.
// flow: (2,128,128,128,3) fp32. vec = flow/128; 7x: vec += trilinear(vec, grid+vec).
//
// Round 7: ONE cooperative kernel. Each thread owns 16 voxels (grid-stride),
// keeps their velocity in fp32 REGISTERS across all phases (no own-vec reload,
// no convert pass, no dispatch boundaries). Field written to memory as half4
// each phase only so OTHER threads can gather it; grid.sync() (agent-scope
// fence) between phases handles cross-XCD L2 visibility. Gathers use the r6
// 16B w-pair trick (4 gather instrs/voxel). Fallback: r6 multi-kernel path.

#define DIM 128
#define VOLN (DIM * DIM * DIM)
#define NBATCH 2
#define TOTVOX (NBATCH * VOLN)   // 4,194,304 = 2^22

#define CBLOCKS 1024
#define CTHREADS 256
#define CHUNKS (TOTVOX / (CBLOCKS * CTHREADS))   // 16
#define CSTRIDE (CBLOCKS * CTHREADS)             // 262,144 = 2^18

union H4 {
    uint2 u;
    __half2 h[2];
};

struct __align__(8) HPair {   // two adjacent half4 voxels; 16B, 8B-aligned
    uint2 lo, hi;
};

__device__ __forceinline__ float clamp127f(float x) {
    return fminf(fmaxf(x, 0.0f), 127.0f);
}

// one integration step for one voxel: v += trilinear(field, x + v).
// vb = batch base of half4 field; v kept fp32 in registers.
__device__ __forceinline__ void step_vox(const uint2* __restrict__ vb, int vid,
                                         float& vx, float& vy, float& vz) {
    int w = vid & 127;
    int h = (vid >> 7) & 127;
    int d = (vid >> 14) & 127;

    float ld = clamp127f((float)d + vx);
    float lh = clamp127f((float)h + vy);
    float lw = clamp127f((float)w + vz);

    float fd = floorf(ld), fh = floorf(lh), fw = floorf(lw);
    int id0 = (int)fd, ih0 = (int)fh, iw0 = (int)fw;
    int id1 = min(id0 + 1, 127);
    int ih1 = min(ih0 + 1, 127);
    float td = ld - fd, th = lh - fh, tw = lw - fw;

    // w-pair base: load [iwlo, iwlo+1]; sel only when iw0==127 (then tw==0)
    int iwlo = min(iw0, 126);
    bool sel = (iw0 > iwlo);

    int r00 = (id0 * DIM + ih0) * DIM + iwlo;
    int r01 = (id0 * DIM + ih1) * DIM + iwlo;
    int r10 = (id1 * DIM + ih0) * DIM + iwlo;
    int r11 = (id1 * DIM + ih1) * DIM + iwlo;

    HPair p00 = *reinterpret_cast<const HPair*>(vb + r00);
    HPair p01 = *reinterpret_cast<const HPair*>(vb + r01);
    HPair p10 = *reinterpret_cast<const HPair*>(vb + r10);
    HPair p11 = *reinterpret_cast<const HPair*>(vb + r11);

    H4 c000, c001, c010, c011, c100, c101, c110, c111;
    c000.u = sel ? p00.hi : p00.lo;  c001.u = p00.hi;
    c010.u = sel ? p01.hi : p01.lo;  c011.u = p01.hi;
    c100.u = sel ? p10.hi : p10.lo;  c101.u = p10.hi;
    c110.u = sel ? p11.hi : p11.lo;  c111.u = p11.hi;

    float wd0 = 1.f - td, wh0 = 1.f - th, ww0 = 1.f - tw;
    float w000 = wd0 * wh0 * ww0, w001 = wd0 * wh0 * tw;
    float w010 = wd0 * th * ww0,  w011 = wd0 * th * tw;
    float w100 = td * wh0 * ww0,  w101 = td * wh0 * tw;
    float w110 = td * th * ww0,   w111 = td * th * tw;

    float ax = 0.f, ay = 0.f, az = 0.f;
#define ACC(WT, C)                                           \
    ax = fmaf(WT, __low2float((C).h[0]), ax);                \
    ay = fmaf(WT, __high2float((C).h[0]), ay);               \
    az = fmaf(WT, __low2float((C).h[1]), az);
    ACC(w000, c000) ACC(w001, c001) ACC(w010, c010) ACC(w011, c011)
    ACC(w100, c100) ACC(w101, c101) ACC(w110, c110) ACC(w111, c111)
#undef ACC

    vx += ax; vy += ay; vz += az;
}

// ---------------- cooperative mono-kernel ----------------
__global__ __launch_bounds__(CTHREADS, 4) void vi_coop(const float* __restrict__ flow,
                                                       uint2* __restrict__ A,
                                                       uint2* __restrict__ B,
                                                       float* __restrict__ out) {
    cg::grid_group grid = cg::this_grid();
    int gtid = blockIdx.x * blockDim.x + threadIdx.x;   // [0, 2^18)
    const float s = 1.f / 128.f;

    float vx[CHUNKS], vy[CHUNKS], vz[CHUNKS];

    // phase 0: read flow (coalesced dwords), scale into regs, publish half4 A
#pragma unroll
    for (int c = 0; c < CHUNKS; ++c) {
        int vid = gtid + (c << 18);
        size_t b3 = (size_t)vid * 3;
        vx[c] = flow[b3 + 0] * s;
        vy[c] = flow[b3 + 1] * s;
        vz[c] = flow[b3 + 2] * s;
        H4 o;
        o.h[0] = __floats2half2_rn(vx[c], vy[c]);
        o.h[1] = __floats2half2_rn(vz[c], 0.f);
        A[vid] = o.u;
    }
    grid.sync();

    // phases 1..6: gather from src, update regs, publish half4 to dst
    uint2* bufs[2] = {A, B};
#pragma unroll 1
    for (int p = 0; p < 6; ++p) {
        const uint2* src = bufs[p & 1];
        uint2* dst = bufs[(p & 1) ^ 1];
#pragma unroll
        for (int c = 0; c < CHUNKS; ++c) {
            int vid = gtid + (c << 18);
            const uint2* vb = src + ((size_t)(vid >> 21) << 21);
            step_vox(vb, vid, vx[c], vy[c], vz[c]);
            H4 o;
            o.h[0] = __floats2half2_rn(vx[c], vy[c]);
            o.h[1] = __floats2half2_rn(vz[c], 0.f);
            dst[vid] = o.u;
        }
        grid.sync();
    }

    // phase 7: gather from A (after 6 swaps the field is back in A), write fp32
#pragma unroll
    for (int c = 0; c < CHUNKS; ++c) {
        int vid = gtid + (c << 18);
        const uint2* vb = (const uint2*)A + ((size_t)(vid >> 21) << 21);
        step_vox(vb, vid, vx[c], vy[c], vz[c]);
        size_t b3 = (size_t)vid * 3;
        out[b3 + 0] = vx[c];
        out[b3 + 1] = vy[c];
        out[b3 + 2] = vz[c];
    }
}

// ---------------- r6 fallback kernels ----------------

__global__ __launch_bounds__(256) void vi_convert_h(const float4* __restrict__ in,
                                                    uint2* __restrict__ out,
                                                    float s) {
    int t = blockIdx.x * blockDim.x + threadIdx.x;
    float4 p0 = in[3 * t + 0];
    float4 p1 = in[3 * t + 1];
    float4 p2 = in[3 * t + 2];
    H4 o0, o1, o2, o3;
    o0.h[0] = __floats2half2_rn(p0.x * s, p0.y * s);
    o0.h[1] = __floats2half2_rn(p0.z * s, 0.f);
    o1.h[0] = __floats2half2_rn(p0.w * s, p1.x * s);
    o1.h[1] = __floats2half2_rn(p1.y * s, 0.f);
    o2.h[0] = __floats2half2_rn(p1.z * s, p1.w * s);
    o2.h[1] = __floats2half2_rn(p2.x * s, 0.f);
    o3.h[0] = __floats2half2_rn(p2.y * s, p2.z * s);
    o3.h[1] = __floats2half2_rn(p2.w * s, 0.f);
    size_t o = (size_t)t * 4;
    out[o + 0] = o0.u;
    out[o + 1] = o1.u;
    out[o + 2] = o2.u;
    out[o + 3] = o3.u;
}

template <bool OUT_F32>
__global__ __launch_bounds__(256) void vi_stepp(const uint2* __restrict__ vin,
                                                void* __restrict__ vout_) {
    int tid = blockIdx.x * blockDim.x + threadIdx.x;
    const uint2* __restrict__ vb = vin + ((size_t)(tid >> 21) << 21);

    H4 v; v.u = vin[tid];
    float vx = __low2float(v.h[0]);
    float vy = __high2float(v.h[0]);
    float vz = __low2float(v.h[1]);

    step_vox(vb, tid, vx, vy, vz);

    if (OUT_F32) {
        float* vout = (float*)vout_;
        size_t base = (size_t)tid * 3;
        vout[base + 0] = vx;
        vout[base + 1] = vy;
        vout[base + 2] = vz;
    } else {
        H4 o;
        o.h[0] = __floats2half2_rn(vx, vy);
        o.h[1] = __floats2half2_rn(vz, 0.f);
        ((uint2*)vout_)[tid] = o.u;
    }
}

// packed fp32 fallback (tiny ws)
__global__ __launch_bounds__(256) void vecint_step(const float* __restrict__ vin,
                                                   float* __restrict__ vout,
                                                   float scale) {
    int tid = blockIdx.x * blockDim.x + threadIdx.x;
    int w = tid & 127;
    int h = (tid >> 7) & 127;
    int d = (tid >> 14) & 127;
    int b = tid >> 21;

    const float* __restrict__ vb = vin + (size_t)b * (VOLN * 3);
    size_t base = (size_t)tid * 3;

    float v0 = vin[base + 0] * scale;
    float v1 = vin[base + 1] * scale;
    float v2 = vin[base + 2] * scale;

    float ld = clamp127f((float)d + v0);
    float lh = clamp127f((float)h + v1);
    float lw = clamp127f((float)w + v2);

    float fd0 = floorf(ld), fh0 = floorf(lh), fw0 = floorf(lw);
    int id0 = (int)fd0, ih0 = (int)fh0, iw0 = (int)fw0;
    float td = ld - fd0, th = lh - fh0, tw = lw - fw0;
    int id1 = min(id0 + 1, 127);
    int ih1 = min(ih0 + 1, 127);
    int iw1 = min(iw0 + 1, 127);

    float wd0 = 1.0f - td, wh0 = 1.0f - th, ww0 = 1.0f - tw;
    float a0 = 0.0f, a1 = 0.0f, a2 = 0.0f;

#define CORNER(IDD, IHH, IWW, WGT)                                  \
    {                                                               \
        int flat = (((IDD) * DIM + (IHH)) * DIM + (IWW)) * 3;       \
        float g = (WGT);                                            \
        a0 = fmaf(g, vb[flat + 0], a0);                             \
        a1 = fmaf(g, vb[flat + 1], a1);                             \
        a2 = fmaf(g, vb[flat + 2], a2);                             \
    }
    CORNER(id0, ih0, iw0, wd0 * wh0 * ww0)
    CORNER(id0, ih0, iw1, wd0 * wh0 * tw)
    CORNER(id0, ih1, iw0, wd0 * th * ww0)
    CORNER(id0, ih1, iw1, wd0 * th * tw)
    CORNER(id1, ih0, iw0, td * wh0 * ww0)
    CORNER(id1, ih0, iw1, td * wh0 * tw)
    CORNER(id1, ih1, iw0, td * th * ww0)
    CORNER(id1, ih1, iw1, td * th * tw)
#undef CORNER

    vout[base + 0] = v0 + a0;
    vout[base + 1] = v1 + a1;
    vout[base + 2] = v2 + a2;
}

// ---------------- launch ----------------

extern "C" void kernel_launch(void* const* d_in, const int* in_sizes, int n_in,
                              void* d_out, int out_size, void* d_ws, size_t ws_size,
                              hipStream_t stream) {
    const float* flow = (const float*)d_in[0];
    float* out = (float*)d_out;
    const size_t HBUF = (size_t)TOTVOX * sizeof(uint2);  // 33.55 MB

    if (ws_size >= 2 * HBUF) {
        uint2* A = (uint2*)d_ws;
        uint2* B = A + TOTVOX;

        // try the cooperative mono-kernel first
        void* args[] = {(void*)&flow, (void*)&A, (void*)&B, (void*)&out};
        hipError_t e = hipLaunchCooperativeKernel((const void*)vi_coop,
                                                  dim3(CBLOCKS), dim3(CTHREADS),
                                                  args, 0, stream);
        if (e == hipSuccess) return;

        // fallback: r6 multi-kernel path
        const int threads = 256;
        const int sblocks = TOTVOX / threads;
        vi_convert_h<<<TOTVOX / 4 / threads, threads, 0, stream>>>(
            (const float4*)flow, A, 1.0f / 128.0f);
        vi_stepp<false><<<sblocks, threads, 0, stream>>>(A, B);
        vi_stepp<false><<<sblocks, threads, 0, stream>>>(B, A);
        vi_stepp<false><<<sblocks, threads, 0, stream>>>(A, B);
        vi_stepp<false><<<sblocks, threads, 0, stream>>>(B, A);
        vi_stepp<false><<<sblocks, threads, 0, stream>>>(A, B);
        vi_stepp<false><<<sblocks, threads, 0, stream>>>(B, A);
        vi_stepp<true ><<<sblocks, threads, 0, stream>>>(A, out);
    } else {
        float* ws = (float*)d_ws;
        const int blocks = TOTVOX / 256;
        const float s = 1.0f / 128.0f;
        vecint_step<<<blocks, 256, 0, stream>>>(flow, out, s);
        vecint_step<<<blocks, 256, 0, stream>>>(out, ws, 1.f);
        vecint_step<<<blocks, 256, 0, stream>>>(ws, out, 1.f);
        vecint_step<<<blocks, 256, 0, stream>>>(out, ws, 1.f);
        vecint_step<<<blocks, 256, 0, stream>>>(ws, out, 1.f);
        vecint_step<<<blocks, 256, 0, stream>>>(out, ws, 1.f);
        vecint_step<<<blocks, 256, 0, stream>>>(ws, out, 1.f);
    }
}

// Round 8
// 170.500 us; speedup vs baseline: 6.3710x; 6.3710x over previous
//
#include <hip/hip_runtime.h>
#include <hip/hip_fp16.h>

// VecInt: scaling-and-squaring integration of stationary velocity field.
// flow: (2,128,128,128,3) fp32. vec = flow/128; 7x: vec += trilinear(vec, grid+vec).
//
// Round 8: r6 structure (half4 field, 16B w-pair gathers, 4 gather instrs/voxel)
// + XCD-chunked block swizzle. Default round-robin block->XCD placement puts
// halo-sharing blocks (adjacent h,d) on different XCDs, thrashing per-XCD L2s.
// Swizzle bid = (p%8)*2048 + p/8 gives each XCD a contiguous 32-d-slice slab
// (4.2 MB ~ its 4 MB L2) processed in h-then-d streaming order.

#define DIM 128
#define VOLN (DIM * DIM * DIM)
#define NBATCH 2
#define TOTVOX (NBATCH * VOLN)   // 4,194,304 = 2^22

union H4 {
    uint2 u;
    __half2 h[2];
};

struct __align__(8) HPair {   // two adjacent half4 voxels; 16B, 8B-aligned
    uint2 lo, hi;
};

__device__ __forceinline__ float clamp127f(float x) {
    return fminf(fmaxf(x, 0.0f), 127.0f);
}

// one integration step for one voxel: v += trilinear(field, x + v).
__device__ __forceinline__ void step_vox(const uint2* __restrict__ vb, int vid,
                                         float& vx, float& vy, float& vz) {
    int w = vid & 127;
    int h = (vid >> 7) & 127;
    int d = (vid >> 14) & 127;

    float ld = clamp127f((float)d + vx);
    float lh = clamp127f((float)h + vy);
    float lw = clamp127f((float)w + vz);

    float fd = floorf(ld), fh = floorf(lh), fw = floorf(lw);
    int id0 = (int)fd, ih0 = (int)fh, iw0 = (int)fw;
    int id1 = min(id0 + 1, 127);
    int ih1 = min(ih0 + 1, 127);
    float td = ld - fd, th = lh - fh, tw = lw - fw;

    // w-pair base: load [iwlo, iwlo+1]; sel only when iw0==127 (then tw==0)
    int iwlo = min(iw0, 126);
    bool sel = (iw0 > iwlo);

    int r00 = (id0 * DIM + ih0) * DIM + iwlo;
    int r01 = (id0 * DIM + ih1) * DIM + iwlo;
    int r10 = (id1 * DIM + ih0) * DIM + iwlo;
    int r11 = (id1 * DIM + ih1) * DIM + iwlo;

    HPair p00 = *reinterpret_cast<const HPair*>(vb + r00);
    HPair p01 = *reinterpret_cast<const HPair*>(vb + r01);
    HPair p10 = *reinterpret_cast<const HPair*>(vb + r10);
    HPair p11 = *reinterpret_cast<const HPair*>(vb + r11);

    H4 c000, c001, c010, c011, c100, c101, c110, c111;
    c000.u = sel ? p00.hi : p00.lo;  c001.u = p00.hi;
    c010.u = sel ? p01.hi : p01.lo;  c011.u = p01.hi;
    c100.u = sel ? p10.hi : p10.lo;  c101.u = p10.hi;
    c110.u = sel ? p11.hi : p11.lo;  c111.u = p11.hi;

    float wd0 = 1.f - td, wh0 = 1.f - th, ww0 = 1.f - tw;
    float w000 = wd0 * wh0 * ww0, w001 = wd0 * wh0 * tw;
    float w010 = wd0 * th * ww0,  w011 = wd0 * th * tw;
    float w100 = td * wh0 * ww0,  w101 = td * wh0 * tw;
    float w110 = td * th * ww0,   w111 = td * th * tw;

    float ax = 0.f, ay = 0.f, az = 0.f;
#define ACC(WT, C)                                           \
    ax = fmaf(WT, __low2float((C).h[0]), ax);                \
    ay = fmaf(WT, __high2float((C).h[0]), ay);               \
    az = fmaf(WT, __low2float((C).h[1]), az);
    ACC(w000, c000) ACC(w001, c001) ACC(w010, c010) ACC(w011, c011)
    ACC(w100, c100) ACC(w101, c101) ACC(w110, c110) ACC(w111, c111)
#undef ACC

    vx += ax; vy += ay; vz += az;
}

// ---------------- convert: packed fp32*3 -> half4 with scale ----------------
__global__ __launch_bounds__(256) void vi_convert_h(const float4* __restrict__ in,
                                                    uint2* __restrict__ out,
                                                    float s) {
    int t = blockIdx.x * blockDim.x + threadIdx.x;
    float4 p0 = in[3 * t + 0];
    float4 p1 = in[3 * t + 1];
    float4 p2 = in[3 * t + 2];
    H4 o0, o1, o2, o3;
    o0.h[0] = __floats2half2_rn(p0.x * s, p0.y * s);
    o0.h[1] = __floats2half2_rn(p0.z * s, 0.f);
    o1.h[0] = __floats2half2_rn(p0.w * s, p1.x * s);
    o1.h[1] = __floats2half2_rn(p1.y * s, 0.f);
    o2.h[0] = __floats2half2_rn(p1.z * s, p1.w * s);
    o2.h[1] = __floats2half2_rn(p2.x * s, 0.f);
    o3.h[0] = __floats2half2_rn(p2.y * s, p2.z * s);
    o3.h[1] = __floats2half2_rn(p2.w * s, 0.f);
    size_t o = (size_t)t * 4;
    out[o + 0] = o0.u;
    out[o + 1] = o1.u;
    out[o + 2] = o2.u;
    out[o + 3] = o3.u;
}

// ---------------- step: pair-load gathers + XCD-chunked swizzle ----------------
// grid MUST be 16384 blocks x 256 threads. OUT_F32: final step -> packed fp32.
template <bool OUT_F32>
__global__ __launch_bounds__(256) void vi_stepp(const uint2* __restrict__ vin,
                                                void* __restrict__ vout_) {
    // XCD-chunked bijective swizzle: physical block p (XCD = p%8 round-robin)
    // -> logical block (p%8)*2048 + p/8, so XCD x owns contiguous logical
    // range [x*2048, (x+1)*2048) = one 32-d-slice slab, streamed h-then-d.
    int p = blockIdx.x;
    int bid = ((p & 7) << 11) + (p >> 3);
    int tid = bid * 256 + (int)threadIdx.x;   // voxel id

    const uint2* __restrict__ vb = vin + ((size_t)(tid >> 21) << 21);  // batch base

    H4 v; v.u = vin[tid];
    float vx = __low2float(v.h[0]);
    float vy = __high2float(v.h[0]);
    float vz = __low2float(v.h[1]);

    step_vox(vb, tid, vx, vy, vz);

    if (OUT_F32) {
        float* vout = (float*)vout_;
        size_t base = (size_t)tid * 3;
        vout[base + 0] = vx;
        vout[base + 1] = vy;
        vout[base + 2] = vz;
    } else {
        H4 o;
        o.h[0] = __floats2half2_rn(vx, vy);
        o.h[1] = __floats2half2_rn(vz, 0.f);
        ((uint2*)vout_)[tid] = o.u;
    }
}

// ---------------- packed fp32 fallback (tiny ws) ----------------
__global__ __launch_bounds__(256) void vecint_step(const float* __restrict__ vin,
                                                   float* __restrict__ vout,
                                                   float scale) {
    int tid = blockIdx.x * blockDim.x + threadIdx.x;
    int w = tid & 127;
    int h = (tid >> 7) & 127;
    int d = (tid >> 14) & 127;
    int b = tid >> 21;

    const float* __restrict__ vb = vin + (size_t)b * (VOLN * 3);
    size_t base = (size_t)tid * 3;

    float v0 = vin[base + 0] * scale;
    float v1 = vin[base + 1] * scale;
    float v2 = vin[base + 2] * scale;

    float ld = clamp127f((float)d + v0);
    float lh = clamp127f((float)h + v1);
    float lw = clamp127f((float)w + v2);

    float fd0 = floorf(ld), fh0 = floorf(lh), fw0 = floorf(lw);
    int id0 = (int)fd0, ih0 = (int)fh0, iw0 = (int)fw0;
    float td = ld - fd0, th = lh - fh0, tw = lw - fw0;
    int id1 = min(id0 + 1, 127);
    int ih1 = min(ih0 + 1, 127);
    int iw1 = min(iw0 + 1, 127);

    float wd0 = 1.0f - td, wh0 = 1.0f - th, ww0 = 1.0f - tw;
    float a0 = 0.0f, a1 = 0.0f, a2 = 0.0f;

#define CORNER(IDD, IHH, IWW, WGT)                                  \
    {                                                               \
        int flat = (((IDD) * DIM + (IHH)) * DIM + (IWW)) * 3;       \
        float g = (WGT);                                            \
        a0 = fmaf(g, vb[flat + 0], a0);                             \
        a1 = fmaf(g, vb[flat + 1], a1);                             \
        a2 = fmaf(g, vb[flat + 2], a2);                             \
    }
    CORNER(id0, ih0, iw0, wd0 * wh0 * ww0)
    CORNER(id0, ih0, iw1, wd0 * wh0 * tw)
    CORNER(id0, ih1, iw0, wd0 * th * ww0)
    CORNER(id0, ih1, iw1, wd0 * th * tw)
    CORNER(id1, ih0, iw0, td * wh0 * ww0)
    CORNER(id1, ih0, iw1, td * wh0 * tw)
    CORNER(id1, ih1, iw0, td * th * ww0)
    CORNER(id1, ih1, iw1, td * th * tw)
#undef CORNER

    vout[base + 0] = v0 + a0;
    vout[base + 1] = v1 + a1;
    vout[base + 2] = v2 + a2;
}

// ---------------- launch ----------------

extern "C" void kernel_launch(void* const* d_in, const int* in_sizes, int n_in,
                              void* d_out, int out_size, void* d_ws, size_t ws_size,
                              hipStream_t stream) {
    const float* flow = (const float*)d_in[0];
    float* out = (float*)d_out;
    const size_t HBUF = (size_t)TOTVOX * sizeof(uint2);  // 33.55 MB

    if (ws_size >= 2 * HBUF) {
        uint2* A = (uint2*)d_ws;
        uint2* B = A + TOTVOX;
        const int threads = 256;
        const int sblocks = TOTVOX / threads;   // 16384
        vi_convert_h<<<TOTVOX / 4 / threads, threads, 0, stream>>>(
            (const float4*)flow, A, 1.0f / 128.0f);
        vi_stepp<false><<<sblocks, threads, 0, stream>>>(A, B);   // 1
        vi_stepp<false><<<sblocks, threads, 0, stream>>>(B, A);   // 2
        vi_stepp<false><<<sblocks, threads, 0, stream>>>(A, B);   // 3
        vi_stepp<false><<<sblocks, threads, 0, stream>>>(B, A);   // 4
        vi_stepp<false><<<sblocks, threads, 0, stream>>>(A, B);   // 5
        vi_stepp<false><<<sblocks, threads, 0, stream>>>(B, A);   // 6
        vi_stepp<true ><<<sblocks, threads, 0, stream>>>(A, out); // 7
    } else {
        // fallback: packed fp32 ping-pong between out and ws
        float* ws = (float*)d_ws;
        const int blocks = TOTVOX / 256;
        const float s = 1.0f / 128.0f;
        vecint_step<<<blocks, 256, 0, stream>>>(flow, out, s);
        vecint_step<<<blocks, 256, 0, stream>>>(out, ws, 1.f);
        vecint_step<<<blocks, 256, 0, stream>>>(ws, out, 1.f);
        vecint_step<<<blocks, 256, 0, stream>>>(out, ws, 1.f);
        vecint_step<<<blocks, 256, 0, stream>>>(ws, out, 1.f);
        vecint_step<<<blocks, 256, 0, stream>>>(out, ws, 1.f);
        vecint_step<<<blocks, 256, 0, stream>>>(ws, out, 1.f);
    }
}